// Round 8
// baseline (2482.801 us; speedup 1.0000x reference)
//
#include <hip/hip_runtime.h>

#define B 4096
#define J 16
#define HID 128
#define INTER 64
#define NLAYERS 4
#define NEGV -9000000000000000.0f
#define ELEMS ((size_t)B*16*128)
#define NREP 32
#define SLOT 8192   // NREP*256

typedef __attribute__((ext_vector_type(8))) short short8;
typedef __attribute__((ext_vector_type(4))) float f32x4;

static __device__ __forceinline__ unsigned short f2bf(float x) {
    unsigned u = __float_as_uint(x);
    unsigned r = u + 0x7fffu + ((u >> 16) & 1u);
    return (unsigned short)(r >> 16);
}
static __device__ __forceinline__ void splitbf(float x, unsigned short& h, unsigned short& l) {
    h = f2bf(x);
    float hf = __uint_as_float((unsigned)h << 16);
    l = f2bf(x - hf);
}
static __device__ __forceinline__ void splitbf4(float4 v, uint2& hh, uint2& ll) {
    unsigned short h0,l0,h1,l1,h2,l2,h3,l3;
    splitbf(v.x,h0,l0); splitbf(v.y,h1,l1); splitbf(v.z,h2,l2); splitbf(v.w,h3,l3);
    hh = make_uint2((unsigned)h0 | ((unsigned)h1<<16), (unsigned)h2 | ((unsigned)h3<<16));
    ll = make_uint2((unsigned)l0 | ((unsigned)l1<<16), (unsigned)l2 | ((unsigned)l3<<16));
}
static __device__ __forceinline__ f32x4 mfma16(short8 a, short8 b, f32x4 c) {
    return __builtin_amdgcn_mfma_f32_16x16x32_bf16(a, b, c, 0, 0, 0);
}
static __device__ __forceinline__ f32x4 mfma_split(short8 ah, short8 al,
                                                   short8 bh, short8 bl, f32x4 acc) {
    acc = mfma16(ah, bh, acc);
    acc = mfma16(ah, bl, acc);
    acc = mfma16(al, bh, acc);
    return acc;
}
static __device__ __forceinline__ float bfpair(unsigned short h, unsigned short l) {
    return __uint_as_float((unsigned)h << 16) + __uint_as_float((unsigned)l << 16);
}

// ---------------------------------------------------------------- adjacency
__global__ void adj_kernel(const float* __restrict__ e_in,
                           const float* __restrict__ e_res,
                           const float* __restrict__ e_out,
                           const int* __restrict__ rows,
                           const int* __restrict__ cols, int nnz,
                           float* __restrict__ off_all,
                           float* __restrict__ diag_all) {
    int m = blockIdx.x;
    int i = threadIdx.x;
    const float* e = (m == 0) ? e_in : (m <= 8) ? e_res + (size_t)(m - 1) * nnz : e_out;
    float l[16];
    for (int j = 0; j < 16; j++) l[j] = NEGV;
    for (int k = 0; k < nnz; k++)
        if (rows[k] == i) l[cols[k]] = e[k];
    float mx = l[0];
    for (int j = 1; j < 16; j++) mx = fmaxf(mx, l[j]);
    float ex[16], s = 0.f;
    for (int j = 0; j < 16; j++) { ex[j] = expf(l[j] - mx); s += ex[j]; }
    float inv = 1.f / s;
    for (int j = 0; j < 16; j++) {
        float a = ex[j] * inv;
        if (j == i) { diag_all[m * 16 + i] = a; a = 0.f; }
        off_all[m * 256 + i * 16 + j] = a;
    }
}

// ---------------------------------------------------------------- weight prep
#define WB_N   262144
#define NLW_N  122880
#define NLWW_N 40960
__global__ void prep_w_kernel(const float* __restrict__ W_res,
                              const float* __restrict__ g_w, const float* __restrict__ t_w,
                              const float* __restrict__ p_w, const float* __restrict__ W_w,
                              unsigned short* __restrict__ Wbh, unsigned short* __restrict__ Wbl,
                              unsigned short* __restrict__ nlwh, unsigned short* __restrict__ nlwl,
                              unsigned short* __restrict__ nlWh, unsigned short* __restrict__ nlWl) {
    int i = blockIdx.x * 256 + threadIdx.x;
    unsigned short h, l;
    if (i < WB_N) {
        int lay = i >> 15, rem = i & 32767, n = rem >> 8, k = rem & 255;
        int d = k >> 7, f = k & 127;
        splitbf(W_res[(((lay << 1) | d) * 128 + f) * 128 + n], h, l);
        Wbh[i] = h; Wbl[i] = l;
    } else if (i < WB_N + NLW_N) {
        int j = i - WB_N;
        int lay = j / 24576, r2 = j % 24576;
        int conv = r2 >> 13, oc = r2 & 8191;
        const float* src = conv == 0 ? g_w : conv == 1 ? t_w : p_w;
        splitbf(src[lay * 8192 + oc], h, l);
        nlwh[j] = h; nlwl[j] = l;
    } else if (i < WB_N + NLW_N + NLWW_N) {
        int j = i - WB_N - NLW_N;
        splitbf(W_w[j], h, l);
        nlWh[j] = h; nlWl[j] = l;
    }
}

__global__ void prep_vt_kernel(const float* __restrict__ t_w, const float* __restrict__ t_b,
                               const float* __restrict__ cp_w,
                               float* __restrict__ vt, float* __restrict__ ct) {
    int l = blockIdx.x, c = threadIdx.x;
    float s = 0.f;
    for (int c2 = 0; c2 < 64; c2++)
        s += cp_w[l * 128 + c2] * t_w[(l * 64 + c2) * 128 + c];
    vt[l * 128 + c] = s;
    if (c == 0) {
        float s2 = 0.f;
        for (int c2 = 0; c2 < 64; c2++) s2 += cp_w[l * 128 + c2] * t_b[l * 64 + c2];
        ct[l] = s2;
    }
}

// ---------------------------------------------------------------- stats finalize
__global__ void finalize_kernel(const float* __restrict__ slot, float* __restrict__ fin) {
    __shared__ float sh[256];
    int t = threadIdx.x;
    float s = 0.f;
    #pragma unroll
    for (int r = 0; r < NREP; r++) s += slot[r * 256 + t];
    sh[t] = s;
    __syncthreads();
    if (t < 128) {
        float m = sh[t] * (1.f / 65536.f);
        float v = sh[128 + t] * (1.f / 65536.f) - m * m;
        fin[t] = m;
        fin[128 + t] = rsqrtf(v + 1e-5f);
    }
}

// ---------------------------------------------------------------- gconv in (F=2)
__global__ __launch_bounds__(256) void gconv_in_kernel(
        const float* __restrict__ x, const float* __restrict__ W,
        const float* __restrict__ bias, const float* __restrict__ off,
        const float* __restrict__ diag, float* __restrict__ out,
        float* __restrict__ stats_out) {
    __shared__ float xs[16][2];
    __shared__ float gs[16][2];
    __shared__ float red[512];
    int b = blockIdx.x, t = threadIdx.x;
    if (t < 32) xs[t >> 1][t & 1] = x[b * 32 + t];
    __syncthreads();
    if (t < 32) {
        int i = t >> 1, f = t & 1;
        float g = 0.f;
        #pragma unroll
        for (int j = 0; j < 16; j++) g += off[i * 16 + j] * xs[j][f];
        gs[i][f] = g;
    }
    __syncthreads();
    int o = t & 127;
    float w00 = W[o], w01 = W[128 + o], w10 = W[256 + o], w11 = W[384 + o], bo = bias[o];
    float s = 0.f, q = 0.f;
    for (int idx = t; idx < 2048; idx += 256) {
        int i = idx >> 7;
        float v = diag[i] * (xs[i][0] * w00 + xs[i][1] * w01)
                + gs[i][0] * w10 + gs[i][1] * w11 + bo;
        out[(size_t)b * 2048 + idx] = v;
        s += v; q += v * v;
    }
    red[t] = s; red[256 + t] = q;
    __syncthreads();
    float* so = stats_out + (b & (NREP - 1)) * 256;
    if (t < 128) {
        atomicAdd(&so[t], red[t] + red[t + 128]);
        atomicAdd(&so[128 + t], red[256 + t] + red[256 + t + 128]);
    }
}

// ---------------------------------------------------------------- gconv 128->128
// 4 samples per block (blockIdx.x + s*1024), register-prefetch pipelined.
__global__ __launch_bounds__(256, 6) void gconv_mfma_kernel(
        const float* src, const float* wy,
        const float* __restrict__ fin,
        const float* __restrict__ bn_g, const float* __restrict__ bn_b,
        const int* __restrict__ restored, float* zdst,
        const unsigned short* __restrict__ Wbh,
        const unsigned short* __restrict__ Wbl,
        const float* __restrict__ bias,
        const float* __restrict__ off, const float* __restrict__ diag,
        float* dst, float* __restrict__ stats_out) {
    __shared__ float hraw[16][132];
    __shared__ __align__(16) unsigned short ksh[16][264];
    __shared__ __align__(16) unsigned short ksl[16][264];
    __shared__ float offs[256];
    __shared__ float diags[16];
    int t = threadIdx.x;
    offs[t] = off[t];
    if (t < 16) diags[t] = diag[t];
    int c4 = (4 * t) & 127;
    int r0 = t >> 5;
    float4 m4 = make_float4(0,0,0,0), sc4 = make_float4(0,0,0,0), bb4 = make_float4(0,0,0,0);
    if (fin) {
        m4 = *(const float4*)&fin[c4];
        float4 iv = *(const float4*)&fin[128 + c4];
        float4 g4 = *(const float4*)&bn_g[c4];
        bb4 = *(const float4*)&bn_b[c4];
        sc4 = make_float4(iv.x * g4.x, iv.y * g4.y, iv.z * g4.z, iv.w * g4.w);
    }
    int ro0 = 0, ro1 = 0;
    if (wy) { ro0 = restored[r0]; ro1 = restored[r0 + 8]; }
    const float4* src4 = (const float4*)src;
    const float4* wy4  = (const float4*)wy;
    int b0 = blockIdx.x;
    float4 sv0 = src4[(size_t)b0 * 512 + t];
    float4 sv1 = src4[(size_t)b0 * 512 + 256 + t];
    float4 wv0 = make_float4(0,0,0,0), wv1 = make_float4(0,0,0,0);
    if (wy) {
        wv0 = wy4[(size_t)b0 * 512 + ro0 * 32 + (c4 >> 2)];
        wv1 = wy4[(size_t)b0 * 512 + ro1 * 32 + (c4 >> 2)];
    }
    int wv_ = t >> 6, lane = t & 63;
    int mn = lane & 15, kq = (lane >> 4) << 3, qr = (lane >> 4) << 2;

    for (int s = 0; s < 4; s++) {
        int bb_ = blockIdx.x + s * 1024;
        // ---- phase 0 (prefetched regs)
        {
            float4 v = sv0;
            if (wy) {
                v.x += (wv0.x - m4.x) * sc4.x + bb4.x;
                v.y += (wv0.y - m4.y) * sc4.y + bb4.y;
                v.z += (wv0.z - m4.z) * sc4.z + bb4.z;
                v.w += (wv0.w - m4.w) * sc4.w + bb4.w;
                ((float4*)zdst)[(size_t)bb_ * 512 + t] = v;
            } else if (fin) {
                v.x = fmaxf((v.x - m4.x) * sc4.x + bb4.x, 0.f);
                v.y = fmaxf((v.y - m4.y) * sc4.y + bb4.y, 0.f);
                v.z = fmaxf((v.z - m4.z) * sc4.z + bb4.z, 0.f);
                v.w = fmaxf((v.w - m4.w) * sc4.w + bb4.w, 0.f);
            }
            *(float4*)&hraw[r0][c4] = v;
            v = sv1;
            if (wy) {
                v.x += (wv1.x - m4.x) * sc4.x + bb4.x;
                v.y += (wv1.y - m4.y) * sc4.y + bb4.y;
                v.z += (wv1.z - m4.z) * sc4.z + bb4.z;
                v.w += (wv1.w - m4.w) * sc4.w + bb4.w;
                ((float4*)zdst)[(size_t)bb_ * 512 + 256 + t] = v;
            } else if (fin) {
                v.x = fmaxf((v.x - m4.x) * sc4.x + bb4.x, 0.f);
                v.y = fmaxf((v.y - m4.y) * sc4.y + bb4.y, 0.f);
                v.z = fmaxf((v.z - m4.z) * sc4.z + bb4.z, 0.f);
                v.w = fmaxf((v.w - m4.w) * sc4.w + bb4.w, 0.f);
            }
            *(float4*)&hraw[r0 + 8][c4] = v;
        }
        // ---- prefetch next sample (overlaps mix+MFMA of current)
        if (s < 3) {
            int b1 = blockIdx.x + (s + 1) * 1024;
            sv0 = src4[(size_t)b1 * 512 + t];
            sv1 = src4[(size_t)b1 * 512 + 256 + t];
            if (wy) {
                wv0 = wy4[(size_t)b1 * 512 + ro0 * 32 + (c4 >> 2)];
                wv1 = wy4[(size_t)b1 * 512 + ro1 * 32 + (c4 >> 2)];
            }
        }
        __syncthreads();
        // ---- mix + diag-fold + split
        for (int u = t; u < 512; u += 256) {
            int i = u >> 5, f4 = (u & 31) << 2;
            float4 hv = *(const float4*)&hraw[i][f4];
            float4 g = make_float4(0.f, 0.f, 0.f, 0.f);
            #pragma unroll
            for (int j = 0; j < 16; j++) {
                float w = offs[i * 16 + j];
                float4 hj = *(const float4*)&hraw[j][f4];
                g.x += w * hj.x; g.y += w * hj.y; g.z += w * hj.z; g.w += w * hj.w;
            }
            float d = diags[i];
            uint2 hh, ll;
            splitbf4(make_float4(d * hv.x, d * hv.y, d * hv.z, d * hv.w), hh, ll);
            *(uint2*)&ksh[i][f4] = hh;
            *(uint2*)&ksl[i][f4] = ll;
            splitbf4(g, hh, ll);
            *(uint2*)&ksh[i][128 + f4] = hh;
            *(uint2*)&ksl[i][128 + f4] = ll;
        }
        __syncthreads();
        // ---- MFMA
        int n0 = wv_ << 5;
        f32x4 acc0 = {0.f, 0.f, 0.f, 0.f}, acc1 = {0.f, 0.f, 0.f, 0.f};
        const unsigned short* wh0 = Wbh + (size_t)(n0 + mn) * 256 + kq;
        const unsigned short* wl0 = Wbl + (size_t)(n0 + mn) * 256 + kq;
        #pragma unroll
        for (int k = 0; k < 8; k++) {
            int k0 = k << 5;
            short8 ah = *(const short8*)&ksh[mn][k0 + kq];
            short8 al = *(const short8*)&ksl[mn][k0 + kq];
            acc0 = mfma_split(ah, al, *(const short8*)(wh0 + k0), *(const short8*)(wl0 + k0), acc0);
            acc1 = mfma_split(ah, al, *(const short8*)(wh0 + 4096 + k0), *(const short8*)(wl0 + 4096 + k0), acc1);
        }
        float bias0 = bias[n0 + mn], bias1 = bias[n0 + 16 + mn];
        float s0 = 0.f, q0 = 0.f, s1 = 0.f, q1 = 0.f;
        #pragma unroll
        for (int r = 0; r < 4; r++) {
            int row = qr + r;
            float v0 = acc0[r] + bias0;
            float v1 = acc1[r] + bias1;
            dst[(size_t)bb_ * 2048 + row * 128 + n0 + mn] = v0;
            dst[(size_t)bb_ * 2048 + row * 128 + n0 + 16 + mn] = v1;
            s0 += v0; q0 += v0 * v0; s1 += v1; q1 += v1 * v1;
        }
        s0 += __shfl_xor(s0, 16); s0 += __shfl_xor(s0, 32);
        q0 += __shfl_xor(q0, 16); q0 += __shfl_xor(q0, 32);
        s1 += __shfl_xor(s1, 16); s1 += __shfl_xor(s1, 32);
        q1 += __shfl_xor(q1, 16); q1 += __shfl_xor(q1, 32);
        float* so = stats_out + (bb_ & (NREP - 1)) * 256;
        if (lane < 16) {
            atomicAdd(&so[n0 + mn], s0);
            atomicAdd(&so[128 + n0 + mn], q0);
            atomicAdd(&so[n0 + 16 + mn], s1);
            atomicAdd(&so[128 + n0 + 16 + mn], q1);
        }
        // no trailing barrier needed: next phase 0 writes only hraw, which no
        // post-mix-barrier reader touches; the phase-0 barrier orders ksh reuse.
    }
}

// ---------------------------------------------------------------- nonlocal A
// 2 samples per block (blockIdx.x + s*2048), register-prefetch pipelined.
#define CG(conv, o, j) cgbuf[((conv) * 64 + (o)) * 17 + (j)]
#define WYL(o, j)      cgbuf[(o) * 17 + (j)]
__global__ __launch_bounds__(256, 6) void nl_a_kernel(
        const float* tsrc, const float* __restrict__ fin,
        const float* __restrict__ bn_g, const float* __restrict__ bn_b,
        const float* res,
        const unsigned short* __restrict__ nlwh,
        const unsigned short* __restrict__ nlwl,
        const float* __restrict__ g_b, const float* __restrict__ p_b,
        const float* __restrict__ cpw,
        const float* __restrict__ vt, const float* __restrict__ ctp,
        const unsigned short* __restrict__ nlWh,
        const unsigned short* __restrict__ nlWl,
        const float* __restrict__ W_b,
        const int* __restrict__ restored,
        float* hdst, float* wydst, float* __restrict__ wst) {
    __shared__ __align__(16) unsigned short xch[16][136];
    __shared__ __align__(16) unsigned short xcl[16][136];
    __shared__ float cgbuf[2176];
    __shared__ float gx[64][9];
    __shared__ float tvp[16][4], pvp[8][8];
    __shared__ float tv[16], pv[8];
    __shared__ float vtl[128];
    __shared__ __align__(16) unsigned short ybh[16][72];
    __shared__ __align__(16) unsigned short ybl[16][72];
    int t = threadIdx.x;
    if (t < 128) vtl[t] = vt[t];
    int c4 = (4 * t) & 127;
    int r0 = t >> 5;
    int rg0 = restored[r0], rg1 = restored[r0 + 8];
    float ctv = ctp[0];
    float4 m4 = *(const float4*)&fin[c4];
    float4 iv = *(const float4*)&fin[128 + c4];
    float4 g4 = *(const float4*)&bn_g[c4];
    float4 bb4 = *(const float4*)&bn_b[c4];
    float4 sc4 = make_float4(iv.x * g4.x, iv.y * g4.y, iv.z * g4.z, iv.w * g4.w);
    const float4* tsrc4 = (const float4*)tsrc;
    const float4* res4  = (const float4*)res;
    int wv = t >> 6, lane = t & 63;
    int mn = lane & 15, kq = (lane >> 4) << 3, qr = (lane >> 4) << 2;
    // prefetch sample 0
    int b0 = blockIdx.x;
    float4 sv0 = tsrc4[(size_t)b0 * 512 + t];
    float4 sv1 = tsrc4[(size_t)b0 * 512 + 256 + t];
    float4 rv0 = make_float4(0,0,0,0), rv1 = make_float4(0,0,0,0);
    if (res) {
        rv0 = res4[(size_t)b0 * 512 + t];
        rv1 = res4[(size_t)b0 * 512 + 256 + t];
    }

    for (int s = 0; s < 2; s++) {
        int b = blockIdx.x + s * 2048;
        // -------- phase 0: bn/relu + residual (prefetched regs)
        {
            float4 v = sv0;
            v.x = fmaxf((v.x - m4.x) * sc4.x + bb4.x, 0.f);
            v.y = fmaxf((v.y - m4.y) * sc4.y + bb4.y, 0.f);
            v.z = fmaxf((v.z - m4.z) * sc4.z + bb4.z, 0.f);
            v.w = fmaxf((v.w - m4.w) * sc4.w + bb4.w, 0.f);
            if (res) { v.x += rv0.x; v.y += rv0.y; v.z += rv0.z; v.w += rv0.w; }
            ((float4*)hdst)[(size_t)b * 512 + t] = v;
            uint2 hh, ll;
            splitbf4(v, hh, ll);
            *(uint2*)&xch[rg0][c4] = hh;
            *(uint2*)&xcl[rg0][c4] = ll;
            v = sv1;
            v.x = fmaxf((v.x - m4.x) * sc4.x + bb4.x, 0.f);
            v.y = fmaxf((v.y - m4.y) * sc4.y + bb4.y, 0.f);
            v.z = fmaxf((v.z - m4.z) * sc4.z + bb4.z, 0.f);
            v.w = fmaxf((v.w - m4.w) * sc4.w + bb4.w, 0.f);
            if (res) { v.x += rv1.x; v.y += rv1.y; v.z += rv1.z; v.w += rv1.w; }
            ((float4*)hdst)[(size_t)b * 512 + 256 + t] = v;
            splitbf4(v, hh, ll);
            *(uint2*)&xch[rg1][c4] = hh;
            *(uint2*)&xcl[rg1][c4] = ll;
        }
        // prefetch next sample (overlaps phases 1-6 of current)
        if (s == 0) {
            int b1 = blockIdx.x + 2048;
            sv0 = tsrc4[(size_t)b1 * 512 + t];
            sv1 = tsrc4[(size_t)b1 * 512 + 256 + t];
            if (res) {
                rv0 = res4[(size_t)b1 * 512 + t];
                rv1 = res4[(size_t)b1 * 512 + 256 + t];
            }
        }
        __syncthreads();
        // -------- phase 1: g-conv + p-conv MFMA
        {
            short8 bh[4], bl[4];
            #pragma unroll
            for (int k = 0; k < 4; k++) {
                bh[k] = *(const short8*)&xch[mn][k * 32 + kq];
                bl[k] = *(const short8*)&xcl[mn][k * 32 + kq];
            }
            #pragma unroll
            for (int jj = 0; jj < 2; jj++) {
                int jb = wv + jj * 4;
                int conv = jb >> 2;
                int mt = jb & 3;
                int wbase = (conv == 0) ? 0 : 128;
                const unsigned short* aph = nlwh + (size_t)(wbase + mt * 16 + mn) * 128 + kq;
                const unsigned short* apl = nlwl + (size_t)(wbase + mt * 16 + mn) * 128 + kq;
                f32x4 acc = {0.f, 0.f, 0.f, 0.f};
                #pragma unroll
                for (int k = 0; k < 4; k++)
                    acc = mfma_split(*(const short8*)(aph + k * 32), *(const short8*)(apl + k * 32),
                                     bh[k], bl[k], acc);
                const float* bias = (conv == 0) ? g_b : p_b;
                #pragma unroll
                for (int r = 0; r < 4; r++) {
                    int o = mt * 16 + qr + r;
                    CG(conv, o, mn) = acc[r] + bias[o];
                }
            }
        }
        __syncthreads();
        // -------- phase 2
        if (t < 128) {
            for (int u = t; u < 512; u += 128) {
                int c = u >> 3, w2 = u & 7;
                gx[c][w2] = fmaxf(CG(0, c, 2 * w2), CG(0, c, 2 * w2 + 1));
            }
        } else if (t < 192) {
            int u = t - 128, w2 = u & 7, ch = u >> 3;
            float ss = 0.f;
            for (int c = ch * 8; c < ch * 8 + 8; c++)
                ss += fmaxf(CG(1, c, 2 * w2), CG(1, c, 2 * w2 + 1)) * cpw[64 + c];
            pvp[w2][ch] = ss;
        } else {
            int u = t - 192, j = u & 15, ch = u >> 4;
            float ss = 0.f;
            int c0 = ch * 32;
            for (int c = c0; c < c0 + 32; c += 2) {
                unsigned hh = *(const unsigned*)&xch[j][c];
                unsigned ll = *(const unsigned*)&xcl[j][c];
                float v0 = bfpair((unsigned short)hh, (unsigned short)ll);
                float v1 = bfpair((unsigned short)(hh >> 16), (unsigned short)(ll >> 16));
                ss += vtl[c] * v0 + vtl[c + 1] * v1;
            }
            tvp[j][ch] = ss;
        }
        __syncthreads();
        // -------- phase 3
        if (t < 16) {
            tv[t] = tvp[t][0] + tvp[t][1] + tvp[t][2] + tvp[t][3] + ctv;
        } else if (t < 24) {
            int w2 = t - 16;
            float ss = 0.f;
            #pragma unroll
            for (int ch = 0; ch < 8; ch++) ss += pvp[w2][ch];
            pv[w2] = ss;
        }
        __syncthreads();
        // -------- phase 4
        for (int u = t; u < 1024; u += 256) {
            int j = u >> 6, c = u & 63;
            float ss = 0.f;
            #pragma unroll
            for (int w2 = 0; w2 < 8; w2++)
                ss += fmaxf(tv[j] + pv[w2], 0.f) * gx[c][w2];
            unsigned short h, l;
            splitbf(ss * 0.125f, h, l);
            ybh[j][c] = h; ybl[j][c] = l;
        }
        __syncthreads();
        // -------- phase 5: Wy MFMA
        {
            short8 byh0 = *(const short8*)&ybh[mn][kq];
            short8 byh1 = *(const short8*)&ybh[mn][32 + kq];
            short8 byl0 = *(const short8*)&ybl[mn][kq];
            short8 byl1 = *(const short8*)&ybl[mn][32 + kq];
            #pragma unroll
            for (int mm = 0; mm < 2; mm++) {
                int mt = wv * 2 + mm;
                const unsigned short* aph = nlWh + (size_t)(mt * 16 + mn) * 64 + kq;
                const unsigned short* apl = nlWl + (size_t)(mt * 16 + mn) * 64 + kq;
                f32x4 acc = {0.f, 0.f, 0.f, 0.f};
                acc = mfma_split(*(const short8*)aph, *(const short8*)apl, byh0, byl0, acc);
                acc = mfma_split(*(const short8*)(aph + 32), *(const short8*)(apl + 32), byh1, byl1, acc);
                #pragma unroll
                for (int r = 0; r < 4; r++) {
                    int o = mt * 16 + qr + r;
                    WYL(o, mn) = acc[r] + W_b[o];
                }
            }
        }
        __syncthreads();
        // -------- phase 6: write wy + spread stats
        {
            int c = t & 127;
            float ss = 0.f, qq = 0.f;
            for (int idx = t; idx < 2048; idx += 256) {
                int j = idx >> 7;
                float v = WYL(c, j);
                wydst[(size_t)b * 2048 + idx] = v;
                ss += v; qq += v * v;
            }
            float* red = &gx[0][0];
            red[t] = ss; red[256 + t] = qq;
            __syncthreads();
            float* so = wst + (b & (NREP - 1)) * 256;
            if (t < 128) {
                atomicAdd(&so[t], red[t] + red[t + 128]);
                atomicAdd(&so[128 + t], red[256 + t] + red[256 + t + 128]);
            }
        }
        // next phase 0 writes only xch/xcl; stragglers here only touch red/global.
    }
}

// ---------------------------------------------------------------- gconv out (128->3), fused nl_b
__global__ __launch_bounds__(256) void gconv_out_kernel(
        const float* __restrict__ h, const float* __restrict__ wy,
        const float* __restrict__ fin,
        const float* __restrict__ nlg, const float* __restrict__ nlb,
        const int* __restrict__ restored,
        const float* __restrict__ W,
        const float* __restrict__ bias, const float* __restrict__ off,
        const float* __restrict__ diag, float* __restrict__ out) {
    __shared__ float hs[16][132];
    __shared__ float gsv[16][132];
    __shared__ float offs[256];
    __shared__ float p0[48][4], p1[48][4];
    int b = blockIdx.x, t = threadIdx.x;
    offs[t] = off[t];
    {
        int c = t & 127;
        float mean = fin[c];
        float inv = fin[128 + c] * nlg[c];
        float bb = nlb[c];
        for (int idx = t; idx < 2048; idx += 256) {
            int r = idx >> 7;
            float wval = wy[(size_t)b * 2048 + restored[r] * 128 + c];
            hs[r][c] = (wval - mean) * inv + bb + h[(size_t)b * 2048 + idx];
        }
    }
    __syncthreads();
    for (int idx = t; idx < 2048; idx += 256) {
        int i = idx >> 7, f = idx & 127;
        float g = 0.f;
        #pragma unroll
        for (int j = 0; j < 16; j++) g += offs[i * 16 + j] * hs[j][f];
        gsv[i][f] = g;
    }
    __syncthreads();
    if (t < 192) {
        int oid = t >> 2, chunk = t & 3;
        int i = oid / 3, o = oid % 3;
        float a0 = 0.f, a1 = 0.f;
        int f0 = chunk * 32;
        for (int f = f0; f < f0 + 32; f++) {
            a0 += hs[i][f] * W[f * 3 + o];
            a1 += gsv[i][f] * W[384 + f * 3 + o];
        }
        p0[oid][chunk] = a0; p1[oid][chunk] = a1;
    }
    __syncthreads();
    if (t < 48) {
        int i = t / 3, o = t % 3;
        float a0 = p0[t][0] + p0[t][1] + p0[t][2] + p0[t][3];
        float a1 = p1[t][0] + p1[t][1] + p1[t][2] + p1[t][3];
        out[(size_t)b * 48 + t] = diag[i] * a0 + a1 + bias[o];
    }
}

// ================================================================ launch
extern "C" void kernel_launch(void* const* d_in, const int* in_sizes, int n_in,
                              void* d_out, int out_size, void* d_ws, size_t ws_size,
                              hipStream_t stream) {
    (void)n_in; (void)out_size; (void)ws_size;
    const float* x        = (const float*)d_in[0];
    const float* gc_in_W  = (const float*)d_in[1];
    const float* gc_in_e  = (const float*)d_in[2];
    const float* gc_in_b  = (const float*)d_in[3];
    const float* bn_in_g  = (const float*)d_in[4];
    const float* bn_in_b  = (const float*)d_in[5];
    const float* W_res    = (const float*)d_in[6];
    const float* e_res    = (const float*)d_in[7];
    const float* b_res    = (const float*)d_in[8];
    const float* bng_res  = (const float*)d_in[9];
    const float* bnb_res  = (const float*)d_in[10];
    const float* nl_g_w   = (const float*)d_in[11];
    const float* nl_g_b   = (const float*)d_in[12];
    const float* nl_t_w   = (const float*)d_in[13];
    const float* nl_t_b   = (const float*)d_in[14];
    const float* nl_p_w   = (const float*)d_in[15];
    const float* nl_p_b   = (const float*)d_in[16];
    const float* nl_cp_w  = (const float*)d_in[17];
    const float* nl_W_w   = (const float*)d_in[18];
    const float* nl_W_b   = (const float*)d_in[19];
    const float* nl_bn_g  = (const float*)d_in[20];
    const float* nl_bn_b  = (const float*)d_in[21];
    const float* gc_out_W = (const float*)d_in[22];
    const float* gc_out_e = (const float*)d_in[23];
    const float* gc_out_b = (const float*)d_in[24];
    const int*   mask_rows = (const int*)d_in[25];
    const int*   mask_cols = (const int*)d_in[26];
    const int*   restored  = (const int*)d_in[28];
    int nnz = in_sizes[2];

    float* ws       = (float*)d_ws;
    float* off_all  = ws;                  // 0..2560
    float* diag_all = ws + 2560;           // ..2720
    float* stats    = ws + 2720;           // 14 x 8192 -> ..117408
    float* fin      = ws + 117408;         // 14 x 256 -> ..120992
    float* vt       = ws + 120992;         // 5 x 128 -> ..121632
    float* ct       = ws + 121632;         // 5
    unsigned short* Wbh  = (unsigned short*)(ws + 122880);
    unsigned short* Wbl  = Wbh + WB_N;
    unsigned short* nlwh = Wbl + WB_N;
    unsigned short* nlwl = nlwh + NLW_N;
    unsigned short* nlWh = nlwl + NLW_N;
    unsigned short* nlWl = nlWh + NLWW_N;  // ends at float 548864
    float* Z = ws + 548864;
    float* T = Z + ELEMS;

    hipMemsetAsync(stats, 0, 14 * SLOT * sizeof(float), stream);
    adj_kernel<<<10, 16, 0, stream>>>(gc_in_e, e_res, gc_out_e, mask_rows, mask_cols,
                                      nnz, off_all, diag_all);
    prep_w_kernel<<<(WB_N + NLW_N + NLWW_N + 255) / 256, 256, 0, stream>>>(
        W_res, nl_g_w, nl_t_w, nl_p_w, nl_W_w, Wbh, Wbl, nlwh, nlwl, nlWh, nlWl);
    prep_vt_kernel<<<5, 128, 0, stream>>>(nl_t_w, nl_t_b, nl_cp_w, vt, ct);

    // t0 -> T, slot 0
    gconv_in_kernel<<<B, 256, 0, stream>>>(x, gc_in_W, gc_in_b, off_all, diag_all,
                                           T, stats);
    finalize_kernel<<<1, 256, 0, stream>>>(stats, fin);
    // nonlocal 0: h0 -> Z; wy -> T, slot 1
    nl_a_kernel<<<2048, 256, 0, stream>>>(T, fin, bn_in_g, bn_in_b, nullptr,
                                          nlwh, nlwl, nl_g_b, nl_p_b, nl_cp_w,
                                          vt, ct, nlWh, nlWl, nl_W_b, restored,
                                          Z, T, stats + SLOT);
    finalize_kernel<<<1, 256, 0, stream>>>(stats + SLOT, fin + 256);

    int sl = 1;
    for (int i = 0; i < NLAYERS; i++) {
        int l0 = 2 * i, l1 = 2 * i + 1, li = i + 1;
        // gconv1 + fused nl_b: z -> Z; t1 -> T, slot sl+1
        gconv_mfma_kernel<<<1024, 256, 0, stream>>>(
            Z, T, fin + (size_t)sl * 256,
            nl_bn_g + i * 128, nl_bn_b + i * 128, restored, Z,
            Wbh + (size_t)l0 * 32768, Wbl + (size_t)l0 * 32768, b_res + l0 * 128,
            off_all + (1 + l0) * 256, diag_all + (1 + l0) * 16, T,
            stats + (size_t)(sl + 1) * SLOT);
        finalize_kernel<<<1, 256, 0, stream>>>(stats + (size_t)(sl + 1) * SLOT,
                                               fin + (size_t)(sl + 1) * 256);
        // gconv2: t2 -> T, slot sl+2
        gconv_mfma_kernel<<<1024, 256, 0, stream>>>(
            T, nullptr, fin + (size_t)(sl + 1) * 256,
            bng_res + l0 * 128, bnb_res + l0 * 128, nullptr, nullptr,
            Wbh + (size_t)l1 * 32768, Wbl + (size_t)l1 * 32768, b_res + l1 * 128,
            off_all + (1 + l1) * 256, diag_all + (1 + l1) * 16, T,
            stats + (size_t)(sl + 2) * SLOT);
        finalize_kernel<<<1, 256, 0, stream>>>(stats + (size_t)(sl + 2) * SLOT,
                                               fin + (size_t)(sl + 2) * 256);
        // nl_a: h -> Z; wy -> T, slot sl+3
        nl_a_kernel<<<2048, 256, 0, stream>>>(
            T, fin + (size_t)(sl + 2) * 256,
            bng_res + l1 * 128, bnb_res + l1 * 128, Z,
            nlwh + li * 24576, nlwl + li * 24576,
            nl_g_b + li * 64, nl_p_b + li * 64, nl_cp_w + li * 128,
            vt + li * 128, ct + li, nlWh + li * 8192, nlWl + li * 8192,
            nl_W_b + li * 128, restored, Z, T,
            stats + (size_t)(sl + 3) * SLOT);
        finalize_kernel<<<1, 256, 0, stream>>>(stats + (size_t)(sl + 3) * SLOT,
                                               fin + (size_t)(sl + 3) * 256);
        sl += 3;
    }
    gconv_out_kernel<<<B, 256, 0, stream>>>(Z, T, fin + (size_t)sl * 256,
                                            nl_bn_g + NLAYERS * 128, nl_bn_b + NLAYERS * 128,
                                            restored, gc_out_W, gc_out_b,
                                            off_all + 9 * 256, diag_all + 9 * 16,
                                            (float*)d_out);
}

// Round 9
// 900.020 us; speedup vs baseline: 2.7586x; 2.7586x over previous
//
#include <hip/hip_runtime.h>

#define B 4096
#define J 16
#define HID 128
#define INTER 64
#define NLAYERS 4
#define NEGV -9000000000000000.0f
#define ELEMS ((size_t)B*16*128)
#define NREP 16
#define SLOT 4096

typedef __attribute__((ext_vector_type(8))) short short8;
typedef __attribute__((ext_vector_type(4))) float f32x4;

static __device__ __forceinline__ unsigned short f2bf(float x) {
    unsigned u = __float_as_uint(x);
    unsigned r = u + 0x7fffu + ((u >> 16) & 1u);
    return (unsigned short)(r >> 16);
}
static __device__ __forceinline__ void splitbf(float x, unsigned short& h, unsigned short& l) {
    h = f2bf(x);
    float hf = __uint_as_float((unsigned)h << 16);
    l = f2bf(x - hf);
}
static __device__ __forceinline__ void splitbf4(float4 v, uint2& hh, uint2& ll) {
    unsigned short h0,l0,h1,l1,h2,l2,h3,l3;
    splitbf(v.x,h0,l0); splitbf(v.y,h1,l1); splitbf(v.z,h2,l2); splitbf(v.w,h3,l3);
    hh = make_uint2((unsigned)h0 | ((unsigned)h1<<16), (unsigned)h2 | ((unsigned)h3<<16));
    ll = make_uint2((unsigned)l0 | ((unsigned)l1<<16), (unsigned)l2 | ((unsigned)l3<<16));
}
static __device__ __forceinline__ f32x4 mfma16(short8 a, short8 b, f32x4 c) {
    return __builtin_amdgcn_mfma_f32_16x16x32_bf16(a, b, c, 0, 0, 0);
}
static __device__ __forceinline__ f32x4 mfma_split(short8 ah, short8 al,
                                                   short8 bh, short8 bl, f32x4 acc) {
    acc = mfma16(ah, bh, acc);
    acc = mfma16(ah, bl, acc);
    acc = mfma16(al, bh, acc);
    return acc;
}
static __device__ __forceinline__ float bfpair(unsigned short h, unsigned short l) {
    return __uint_as_float((unsigned)h << 16) + __uint_as_float((unsigned)l << 16);
}

// ---------------------------------------------------------------- adjacency
__global__ void adj_kernel(const float* __restrict__ e_in,
                           const float* __restrict__ e_res,
                           const float* __restrict__ e_out,
                           const int* __restrict__ rows,
                           const int* __restrict__ cols, int nnz,
                           float* __restrict__ off_all,
                           float* __restrict__ diag_all) {
    int m = blockIdx.x;
    int i = threadIdx.x;
    const float* e = (m == 0) ? e_in : (m <= 8) ? e_res + (size_t)(m - 1) * nnz : e_out;
    float l[16];
    for (int j = 0; j < 16; j++) l[j] = NEGV;
    for (int k = 0; k < nnz; k++)
        if (rows[k] == i) l[cols[k]] = e[k];
    float mx = l[0];
    for (int j = 1; j < 16; j++) mx = fmaxf(mx, l[j]);
    float ex[16], s = 0.f;
    for (int j = 0; j < 16; j++) { ex[j] = expf(l[j] - mx); s += ex[j]; }
    float inv = 1.f / s;
    for (int j = 0; j < 16; j++) {
        float a = ex[j] * inv;
        if (j == i) { diag_all[m * 16 + i] = a; a = 0.f; }
        off_all[m * 256 + i * 16 + j] = a;
    }
}

// ---------------------------------------------------------------- weight prep
#define WB_N   262144
#define NLW_N  122880
#define NLWW_N 40960
__global__ void prep_w_kernel(const float* __restrict__ W_res,
                              const float* __restrict__ g_w, const float* __restrict__ t_w,
                              const float* __restrict__ p_w, const float* __restrict__ W_w,
                              unsigned short* __restrict__ Wbh, unsigned short* __restrict__ Wbl,
                              unsigned short* __restrict__ nlwh, unsigned short* __restrict__ nlwl,
                              unsigned short* __restrict__ nlWh, unsigned short* __restrict__ nlWl) {
    int i = blockIdx.x * 256 + threadIdx.x;
    unsigned short h, l;
    if (i < WB_N) {
        int lay = i >> 15, rem = i & 32767, n = rem >> 8, k = rem & 255;
        int d = k >> 7, f = k & 127;
        splitbf(W_res[(((lay << 1) | d) * 128 + f) * 128 + n], h, l);
        Wbh[i] = h; Wbl[i] = l;
    } else if (i < WB_N + NLW_N) {
        int j = i - WB_N;
        int lay = j / 24576, r2 = j % 24576;
        int conv = r2 >> 13, oc = r2 & 8191;
        const float* src = conv == 0 ? g_w : conv == 1 ? t_w : p_w;
        splitbf(src[lay * 8192 + oc], h, l);
        nlwh[j] = h; nlwl[j] = l;
    } else if (i < WB_N + NLW_N + NLWW_N) {
        int j = i - WB_N - NLW_N;
        splitbf(W_w[j], h, l);
        nlWh[j] = h; nlWl[j] = l;
    }
}

__global__ void prep_vt_kernel(const float* __restrict__ t_w, const float* __restrict__ t_b,
                               const float* __restrict__ cp_w,
                               float* __restrict__ vt, float* __restrict__ ct) {
    int l = blockIdx.x, c = threadIdx.x;
    float s = 0.f;
    for (int c2 = 0; c2 < 64; c2++)
        s += cp_w[l * 128 + c2] * t_w[(l * 64 + c2) * 128 + c];
    vt[l * 128 + c] = s;
    if (c == 0) {
        float s2 = 0.f;
        for (int c2 = 0; c2 < 64; c2++) s2 += cp_w[l * 128 + c2] * t_b[l * 64 + c2];
        ct[l] = s2;
    }
}

// ---------------------------------------------------------------- stats finalize
__global__ void finalize_kernel(const float* __restrict__ slot, float* __restrict__ fin) {
    __shared__ float sh[256];
    int t = threadIdx.x;
    float s = 0.f;
    #pragma unroll
    for (int r = 0; r < NREP; r++) s += slot[r * 256 + t];
    sh[t] = s;
    __syncthreads();
    if (t < 128) {
        float m = sh[t] * (1.f / 65536.f);
        float v = sh[128 + t] * (1.f / 65536.f) - m * m;
        fin[t] = m;
        fin[128 + t] = rsqrtf(v + 1e-5f);
    }
}

// ---------------------------------------------------------------- gconv in (F=2)
__global__ __launch_bounds__(256) void gconv_in_kernel(
        const float* __restrict__ x, const float* __restrict__ W,
        const float* __restrict__ bias, const float* __restrict__ off,
        const float* __restrict__ diag, float* __restrict__ out,
        float* __restrict__ stats_out) {
    __shared__ float xs[16][2];
    __shared__ float gs[16][2];
    __shared__ float red[512];
    int b = blockIdx.x, t = threadIdx.x;
    if (t < 32) xs[t >> 1][t & 1] = x[b * 32 + t];
    __syncthreads();
    if (t < 32) {
        int i = t >> 1, f = t & 1;
        float g = 0.f;
        #pragma unroll
        for (int j = 0; j < 16; j++) g += off[i * 16 + j] * xs[j][f];
        gs[i][f] = g;
    }
    __syncthreads();
    int o = t & 127;
    float w00 = W[o], w01 = W[128 + o], w10 = W[256 + o], w11 = W[384 + o], bo = bias[o];
    float s = 0.f, q = 0.f;
    for (int idx = t; idx < 2048; idx += 256) {
        int i = idx >> 7;
        float v = diag[i] * (xs[i][0] * w00 + xs[i][1] * w01)
                + gs[i][0] * w10 + gs[i][1] * w11 + bo;
        out[(size_t)b * 2048 + idx] = v;
        s += v; q += v * v;
    }
    red[t] = s; red[256 + t] = q;
    __syncthreads();
    float* so = stats_out + (b & (NREP - 1)) * 256;
    if (t < 128) {
        atomicAdd(&so[t], red[t] + red[t + 128]);
        atomicAdd(&so[128 + t], red[256 + t] + red[256 + t + 128]);
    }
}

// ---------------------------------------------------------------- gconv 128->128
// (R7 structure: 2 samples per block, register-prefetch; unchanged)
__global__ __launch_bounds__(256) void gconv_mfma_kernel(
        const float* src, const float* wy,
        const float* __restrict__ fin,
        const float* __restrict__ bn_g, const float* __restrict__ bn_b,
        const int* __restrict__ restored, float* zdst,
        const unsigned short* __restrict__ Wbh,
        const unsigned short* __restrict__ Wbl,
        const float* __restrict__ bias,
        const float* __restrict__ off, const float* __restrict__ diag,
        float* dst, float* __restrict__ stats_out) {
    __shared__ float hraw[16][132];
    __shared__ __align__(16) unsigned short ksh[16][264];
    __shared__ __align__(16) unsigned short ksl[16][264];
    __shared__ float offs[256];
    __shared__ float diags[16];
    int t = threadIdx.x;
    offs[t] = off[t];
    if (t < 16) diags[t] = diag[t];
    int c4 = (4 * t) & 127;
    int r0 = t >> 5;
    float4 m4 = make_float4(0,0,0,0), sc4 = make_float4(0,0,0,0), bb4 = make_float4(0,0,0,0);
    if (fin) {
        m4 = *(const float4*)&fin[c4];
        float4 iv = *(const float4*)&fin[128 + c4];
        float4 g4 = *(const float4*)&bn_g[c4];
        bb4 = *(const float4*)&bn_b[c4];
        sc4 = make_float4(iv.x * g4.x, iv.y * g4.y, iv.z * g4.z, iv.w * g4.w);
    }
    int ro0 = 0, ro1 = 0;
    if (wy) { ro0 = restored[r0]; ro1 = restored[r0 + 8]; }
    int b0 = blockIdx.x;
    const float4* src4 = (const float4*)src;
    const float4* wy4  = (const float4*)wy;
    float4 sv0 = src4[(size_t)b0 * 512 + t];
    float4 sv1 = src4[(size_t)b0 * 512 + 256 + t];
    float4 wv0 = make_float4(0,0,0,0), wv1 = make_float4(0,0,0,0);
    if (wy) {
        wv0 = wy4[(size_t)b0 * 512 + ro0 * 32 + (c4 >> 2)];
        wv1 = wy4[(size_t)b0 * 512 + ro1 * 32 + (c4 >> 2)];
    }
    int wv_ = t >> 6, lane = t & 63;
    int mn = lane & 15, kq = (lane >> 4) << 3, qr = (lane >> 4) << 2;

    for (int s = 0; s < 2; s++) {
        int bb_ = blockIdx.x + s * 2048;
        {
            float4 v = sv0;
            if (wy) {
                v.x += (wv0.x - m4.x) * sc4.x + bb4.x;
                v.y += (wv0.y - m4.y) * sc4.y + bb4.y;
                v.z += (wv0.z - m4.z) * sc4.z + bb4.z;
                v.w += (wv0.w - m4.w) * sc4.w + bb4.w;
                ((float4*)zdst)[(size_t)bb_ * 512 + t] = v;
            } else if (fin) {
                v.x = fmaxf((v.x - m4.x) * sc4.x + bb4.x, 0.f);
                v.y = fmaxf((v.y - m4.y) * sc4.y + bb4.y, 0.f);
                v.z = fmaxf((v.z - m4.z) * sc4.z + bb4.z, 0.f);
                v.w = fmaxf((v.w - m4.w) * sc4.w + bb4.w, 0.f);
            }
            *(float4*)&hraw[r0][c4] = v;
            v = sv1;
            if (wy) {
                v.x += (wv1.x - m4.x) * sc4.x + bb4.x;
                v.y += (wv1.y - m4.y) * sc4.y + bb4.y;
                v.z += (wv1.z - m4.z) * sc4.z + bb4.z;
                v.w += (wv1.w - m4.w) * sc4.w + bb4.w;
                ((float4*)zdst)[(size_t)bb_ * 512 + 256 + t] = v;
            } else if (fin) {
                v.x = fmaxf((v.x - m4.x) * sc4.x + bb4.x, 0.f);
                v.y = fmaxf((v.y - m4.y) * sc4.y + bb4.y, 0.f);
                v.z = fmaxf((v.z - m4.z) * sc4.z + bb4.z, 0.f);
                v.w = fmaxf((v.w - m4.w) * sc4.w + bb4.w, 0.f);
            }
            *(float4*)&hraw[r0 + 8][c4] = v;
        }
        if (s == 0) {
            int b1 = blockIdx.x + 2048;
            sv0 = src4[(size_t)b1 * 512 + t];
            sv1 = src4[(size_t)b1 * 512 + 256 + t];
            if (wy) {
                wv0 = wy4[(size_t)b1 * 512 + ro0 * 32 + (c4 >> 2)];
                wv1 = wy4[(size_t)b1 * 512 + ro1 * 32 + (c4 >> 2)];
            }
        }
        __syncthreads();
        for (int u = t; u < 512; u += 256) {
            int i = u >> 5, f4 = (u & 31) << 2;
            float4 hv = *(const float4*)&hraw[i][f4];
            float4 g = make_float4(0.f, 0.f, 0.f, 0.f);
            #pragma unroll
            for (int j = 0; j < 16; j++) {
                float w = offs[i * 16 + j];
                float4 hj = *(const float4*)&hraw[j][f4];
                g.x += w * hj.x; g.y += w * hj.y; g.z += w * hj.z; g.w += w * hj.w;
            }
            float d = diags[i];
            uint2 hh, ll;
            splitbf4(make_float4(d * hv.x, d * hv.y, d * hv.z, d * hv.w), hh, ll);
            *(uint2*)&ksh[i][f4] = hh;
            *(uint2*)&ksl[i][f4] = ll;
            splitbf4(g, hh, ll);
            *(uint2*)&ksh[i][128 + f4] = hh;
            *(uint2*)&ksl[i][128 + f4] = ll;
        }
        __syncthreads();
        int n0 = wv_ << 5;
        f32x4 acc0 = {0.f, 0.f, 0.f, 0.f}, acc1 = {0.f, 0.f, 0.f, 0.f};
        const unsigned short* wh0 = Wbh + (size_t)(n0 + mn) * 256 + kq;
        const unsigned short* wl0 = Wbl + (size_t)(n0 + mn) * 256 + kq;
        #pragma unroll
        for (int k = 0; k < 8; k++) {
            int k0 = k << 5;
            short8 ah = *(const short8*)&ksh[mn][k0 + kq];
            short8 al = *(const short8*)&ksl[mn][k0 + kq];
            acc0 = mfma_split(ah, al, *(const short8*)(wh0 + k0), *(const short8*)(wl0 + k0), acc0);
            acc1 = mfma_split(ah, al, *(const short8*)(wh0 + 4096 + k0), *(const short8*)(wl0 + 4096 + k0), acc1);
        }
        float bias0 = bias[n0 + mn], bias1 = bias[n0 + 16 + mn];
        float s0 = 0.f, q0 = 0.f, s1 = 0.f, q1 = 0.f;
        #pragma unroll
        for (int r = 0; r < 4; r++) {
            int row = qr + r;
            float v0 = acc0[r] + bias0;
            float v1 = acc1[r] + bias1;
            dst[(size_t)bb_ * 2048 + row * 128 + n0 + mn] = v0;
            dst[(size_t)bb_ * 2048 + row * 128 + n0 + 16 + mn] = v1;
            s0 += v0; q0 += v0 * v0; s1 += v1; q1 += v1 * v1;
        }
        s0 += __shfl_xor(s0, 16); s0 += __shfl_xor(s0, 32);
        q0 += __shfl_xor(q0, 16); q0 += __shfl_xor(q0, 32);
        s1 += __shfl_xor(s1, 16); s1 += __shfl_xor(s1, 32);
        q1 += __shfl_xor(q1, 16); q1 += __shfl_xor(q1, 32);
        float* so = stats_out + (bb_ & (NREP - 1)) * 256;
        if (lane < 16) {
            atomicAdd(&so[n0 + mn], s0);
            atomicAdd(&so[128 + n0 + mn], q0);
            atomicAdd(&so[n0 + 16 + mn], s1);
            atomicAdd(&so[128 + n0 + 16 + mn], q1);
        }
        if (s == 0) __syncthreads();
    }
}

// ---------------------------------------------------------------- nonlocal A
// 512 threads, ONE sample per block. 8 waves = 8 MFMA tiles per matmul phase.
#define CG(conv, o, j) cgbuf[((conv) * 64 + (o)) * 17 + (j)]
#define WYL(o, j)      cgbuf[(o) * 17 + (j)]
__global__ __launch_bounds__(512) void nl_a_kernel(
        const float* tsrc, const float* __restrict__ fin,
        const float* __restrict__ bn_g, const float* __restrict__ bn_b,
        const float* res,
        const unsigned short* __restrict__ nlwh,
        const unsigned short* __restrict__ nlwl,
        const float* __restrict__ g_b, const float* __restrict__ p_b,
        const float* __restrict__ cpw,
        const float* __restrict__ vt, const float* __restrict__ ctp,
        const unsigned short* __restrict__ nlWh,
        const unsigned short* __restrict__ nlWl,
        const float* __restrict__ W_b,
        const int* __restrict__ restored,
        float* hdst, float* wydst, float* __restrict__ wst) {
    __shared__ __align__(16) unsigned short xch[16][136];
    __shared__ __align__(16) unsigned short xcl[16][136];
    __shared__ float cgbuf[2176];
    __shared__ float gx[64][9];
    __shared__ float tvp[16][4], pvp[8][8];
    __shared__ float tv[16], pv[8];
    __shared__ float vtl[128];
    __shared__ __align__(16) unsigned short ybh[16][72];
    __shared__ __align__(16) unsigned short ybl[16][72];
    __shared__ float redS[512], redQ[512];
    int b = blockIdx.x, t = threadIdx.x;
    // -------- phase 0: one float4 per thread; bn/relu + residual
    {
        if (t < 128) vtl[t] = vt[t];
        int c4 = (4 * t) & 127;
        int r = t >> 5;
        float4 m4 = *(const float4*)&fin[c4];
        float4 iv = *(const float4*)&fin[128 + c4];
        float4 g4 = *(const float4*)&bn_g[c4];
        float4 bb4 = *(const float4*)&bn_b[c4];
        float4 sc4 = make_float4(iv.x * g4.x, iv.y * g4.y, iv.z * g4.z, iv.w * g4.w);
        float4 v = ((const float4*)tsrc)[(size_t)b * 512 + t];
        v.x = fmaxf((v.x - m4.x) * sc4.x + bb4.x, 0.f);
        v.y = fmaxf((v.y - m4.y) * sc4.y + bb4.y, 0.f);
        v.z = fmaxf((v.z - m4.z) * sc4.z + bb4.z, 0.f);
        v.w = fmaxf((v.w - m4.w) * sc4.w + bb4.w, 0.f);
        if (res) {
            float4 rv = ((const float4*)res)[(size_t)b * 512 + t];
            v.x += rv.x; v.y += rv.y; v.z += rv.z; v.w += rv.w;
        }
        ((float4*)hdst)[(size_t)b * 512 + t] = v;
        int rg = restored[r];
        uint2 hh, ll;
        splitbf4(v, hh, ll);
        *(uint2*)&xch[rg][c4] = hh;
        *(uint2*)&xcl[rg][c4] = ll;
    }
    __syncthreads();
    int w = t >> 6, lane = t & 63;
    int mn = lane & 15, kq = (lane >> 4) << 3, qr = (lane >> 4) << 2;
    // -------- phase 1: g-conv + p-conv MFMA (8 tiles over 8 waves)
    {
        int conv = w >> 2;          // 0=g, 1=p
        int mt = w & 3;
        int wbase = (conv == 0) ? 0 : 128;
        const unsigned short* aph = nlwh + (size_t)(wbase + mt * 16 + mn) * 128 + kq;
        const unsigned short* apl = nlwl + (size_t)(wbase + mt * 16 + mn) * 128 + kq;
        f32x4 acc = {0.f, 0.f, 0.f, 0.f};
        #pragma unroll
        for (int k = 0; k < 4; k++) {
            short8 bh = *(const short8*)&xch[mn][k * 32 + kq];
            short8 bl = *(const short8*)&xcl[mn][k * 32 + kq];
            acc = mfma_split(*(const short8*)(aph + k * 32), *(const short8*)(apl + k * 32),
                             bh, bl, acc);
        }
        const float* bias = (conv == 0) ? g_b : p_b;
        #pragma unroll
        for (int r = 0; r < 4; r++) {
            int o = mt * 16 + qr + r;
            CG(conv, o, mn) = acc[r] + bias[o];
        }
    }
    __syncthreads();
    // -------- phase 2: gx pool (all 512), pvp (t<64), tvp (64<=t<128)
    {
        int c = t >> 3, w2 = t & 7;
        gx[c][w2] = fmaxf(CG(0, c, 2 * w2), CG(0, c, 2 * w2 + 1));
        if (t < 64) {
            int w2b = t & 7, ch = t >> 3;
            float ss = 0.f;
            for (int cc = ch * 8; cc < ch * 8 + 8; cc++)
                ss += fmaxf(CG(1, cc, 2 * w2b), CG(1, cc, 2 * w2b + 1)) * cpw[64 + cc];
            pvp[w2b][ch] = ss;
        } else if (t < 128) {
            int u = t - 64, j = u & 15, ch = u >> 4;
            float ss = 0.f;
            int c0 = ch * 32;
            for (int cc = c0; cc < c0 + 32; cc += 2) {
                unsigned hh = *(const unsigned*)&xch[j][cc];
                unsigned ll = *(const unsigned*)&xcl[j][cc];
                float v0 = bfpair((unsigned short)hh, (unsigned short)ll);
                float v1 = bfpair((unsigned short)(hh >> 16), (unsigned short)(ll >> 16));
                ss += vtl[cc] * v0 + vtl[cc + 1] * v1;
            }
            tvp[j][ch] = ss;
        }
    }
    __syncthreads();
    // -------- phase 3
    if (t < 16) {
        tv[t] = tvp[t][0] + tvp[t][1] + tvp[t][2] + tvp[t][3] + ctp[0];
    } else if (t < 24) {
        int w2 = t - 16;
        float ss = 0.f;
        #pragma unroll
        for (int ch = 0; ch < 8; ch++) ss += pvp[w2][ch];
        pv[w2] = ss;
    }
    __syncthreads();
    // -------- phase 4: y (1024 units over 512 threads)
    #pragma unroll
    for (int u2 = 0; u2 < 2; u2++) {
        int u = t + u2 * 512;
        int j = u >> 6, c = u & 63;
        float ss = 0.f;
        #pragma unroll
        for (int w2 = 0; w2 < 8; w2++)
            ss += fmaxf(tv[j] + pv[w2], 0.f) * gx[c][w2];
        unsigned short h, l;
        splitbf(ss * 0.125f, h, l);
        ybh[j][c] = h; ybl[j][c] = l;
    }
    __syncthreads();
    // -------- phase 5: Wy MFMA (8 tiles over 8 waves)
    {
        int mt = w;
        short8 byh0 = *(const short8*)&ybh[mn][kq];
        short8 byh1 = *(const short8*)&ybh[mn][32 + kq];
        short8 byl0 = *(const short8*)&ybl[mn][kq];
        short8 byl1 = *(const short8*)&ybl[mn][32 + kq];
        const unsigned short* aph = nlWh + (size_t)(mt * 16 + mn) * 64 + kq;
        const unsigned short* apl = nlWl + (size_t)(mt * 16 + mn) * 64 + kq;
        f32x4 acc = {0.f, 0.f, 0.f, 0.f};
        acc = mfma_split(*(const short8*)aph, *(const short8*)apl, byh0, byl0, acc);
        acc = mfma_split(*(const short8*)(aph + 32), *(const short8*)(apl + 32), byh1, byl1, acc);
        #pragma unroll
        for (int r = 0; r < 4; r++) {
            int o = mt * 16 + qr + r;
            WYL(o, mn) = acc[r] + W_b[o];
        }
    }
    __syncthreads();
    // -------- phase 6: write wy + spread stats
    {
        int c = t & 127;
        float ss = 0.f, qq = 0.f;
        #pragma unroll
        for (int u2 = 0; u2 < 4; u2++) {
            int idx = t + u2 * 512;
            int j = idx >> 7;
            float v = WYL(c, j);
            wydst[(size_t)b * 2048 + idx] = v;
            ss += v; qq += v * v;
        }
        redS[t] = ss; redQ[t] = qq;
        __syncthreads();
        float* so = wst + (b & (NREP - 1)) * 256;
        if (t < 128) {
            float s4 = redS[t] + redS[t + 128] + redS[t + 256] + redS[t + 384];
            float q4 = redQ[t] + redQ[t + 128] + redQ[t + 256] + redQ[t + 384];
            atomicAdd(&so[t], s4);
            atomicAdd(&so[128 + t], q4);
        }
    }
}

// ---------------------------------------------------------------- gconv out (128->3), fused nl_b
__global__ __launch_bounds__(256) void gconv_out_kernel(
        const float* __restrict__ h, const float* __restrict__ wy,
        const float* __restrict__ fin,
        const float* __restrict__ nlg, const float* __restrict__ nlb,
        const int* __restrict__ restored,
        const float* __restrict__ W,
        const float* __restrict__ bias, const float* __restrict__ off,
        const float* __restrict__ diag, float* __restrict__ out) {
    __shared__ float hs[16][132];
    __shared__ float gsv[16][132];
    __shared__ float offs[256];
    __shared__ float p0[48][4], p1[48][4];
    int b = blockIdx.x, t = threadIdx.x;
    offs[t] = off[t];
    {
        int c = t & 127;
        float mean = fin[c];
        float inv = fin[128 + c] * nlg[c];
        float bb = nlb[c];
        for (int idx = t; idx < 2048; idx += 256) {
            int r = idx >> 7;
            float wval = wy[(size_t)b * 2048 + restored[r] * 128 + c];
            hs[r][c] = (wval - mean) * inv + bb + h[(size_t)b * 2048 + idx];
        }
    }
    __syncthreads();
    for (int idx = t; idx < 2048; idx += 256) {
        int i = idx >> 7, f = idx & 127;
        float g = 0.f;
        #pragma unroll
        for (int j = 0; j < 16; j++) g += offs[i * 16 + j] * hs[j][f];
        gsv[i][f] = g;
    }
    __syncthreads();
    if (t < 192) {
        int oid = t >> 2, chunk = t & 3;
        int i = oid / 3, o = oid % 3;
        float a0 = 0.f, a1 = 0.f;
        int f0 = chunk * 32;
        for (int f = f0; f < f0 + 32; f++) {
            a0 += hs[i][f] * W[f * 3 + o];
            a1 += gsv[i][f] * W[384 + f * 3 + o];
        }
        p0[oid][chunk] = a0; p1[oid][chunk] = a1;
    }
    __syncthreads();
    if (t < 48) {
        int i = t / 3, o = t % 3;
        float a0 = p0[t][0] + p0[t][1] + p0[t][2] + p0[t][3];
        float a1 = p1[t][0] + p1[t][1] + p1[t][2] + p1[t][3];
        out[(size_t)b * 48 + t] = diag[i] * a0 + a1 + bias[o];
    }
}

// ================================================================ launch
extern "C" void kernel_launch(void* const* d_in, const int* in_sizes, int n_in,
                              void* d_out, int out_size, void* d_ws, size_t ws_size,
                              hipStream_t stream) {
    (void)n_in; (void)out_size; (void)ws_size;
    const float* x        = (const float*)d_in[0];
    const float* gc_in_W  = (const float*)d_in[1];
    const float* gc_in_e  = (const float*)d_in[2];
    const float* gc_in_b  = (const float*)d_in[3];
    const float* bn_in_g  = (const float*)d_in[4];
    const float* bn_in_b  = (const float*)d_in[5];
    const float* W_res    = (const float*)d_in[6];
    const float* e_res    = (const float*)d_in[7];
    const float* b_res    = (const float*)d_in[8];
    const float* bng_res  = (const float*)d_in[9];
    const float* bnb_res  = (const float*)d_in[10];
    const float* nl_g_w   = (const float*)d_in[11];
    const float* nl_g_b   = (const float*)d_in[12];
    const float* nl_t_w   = (const float*)d_in[13];
    const float* nl_t_b   = (const float*)d_in[14];
    const float* nl_p_w   = (const float*)d_in[15];
    const float* nl_p_b   = (const float*)d_in[16];
    const float* nl_cp_w  = (const float*)d_in[17];
    const float* nl_W_w   = (const float*)d_in[18];
    const float* nl_W_b   = (const float*)d_in[19];
    const float* nl_bn_g  = (const float*)d_in[20];
    const float* nl_bn_b  = (const float*)d_in[21];
    const float* gc_out_W = (const float*)d_in[22];
    const float* gc_out_e = (const float*)d_in[23];
    const float* gc_out_b = (const float*)d_in[24];
    const int*   mask_rows = (const int*)d_in[25];
    const int*   mask_cols = (const int*)d_in[26];
    const int*   restored  = (const int*)d_in[28];
    int nnz = in_sizes[2];

    float* ws       = (float*)d_ws;
    float* off_all  = ws;                  // 0..2560
    float* diag_all = ws + 2560;           // ..2720
    float* stats    = ws + 2720;           // 14 x 4096 -> ..60064
    float* fin      = ws + 60064;          // 14 x 256 -> ..63648
    float* vt       = ws + 63664;          // 5 x 128
    float* ct       = ws + 64304;          // 5
    unsigned short* Wbh  = (unsigned short*)(ws + 65536);
    unsigned short* Wbl  = Wbh + WB_N;
    unsigned short* nlwh = Wbl + WB_N;
    unsigned short* nlwl = nlwh + NLW_N;
    unsigned short* nlWh = nlwl + NLW_N;
    unsigned short* nlWl = nlWh + NLWW_N;  // ends at float 491520
    float* Z = ws + 491520;
    float* T = Z + ELEMS;

    hipMemsetAsync(stats, 0, 14 * SLOT * sizeof(float), stream);
    adj_kernel<<<10, 16, 0, stream>>>(gc_in_e, e_res, gc_out_e, mask_rows, mask_cols,
                                      nnz, off_all, diag_all);
    prep_w_kernel<<<(WB_N + NLW_N + NLWW_N + 255) / 256, 256, 0, stream>>>(
        W_res, nl_g_w, nl_t_w, nl_p_w, nl_W_w, Wbh, Wbl, nlwh, nlwl, nlWh, nlWl);
    prep_vt_kernel<<<5, 128, 0, stream>>>(nl_t_w, nl_t_b, nl_cp_w, vt, ct);

    // t0 -> T, slot 0
    gconv_in_kernel<<<B, 256, 0, stream>>>(x, gc_in_W, gc_in_b, off_all, diag_all,
                                           T, stats);
    finalize_kernel<<<1, 256, 0, stream>>>(stats, fin);
    // nonlocal 0: h0 -> Z; wy -> T, slot 1
    nl_a_kernel<<<B, 512, 0, stream>>>(T, fin, bn_in_g, bn_in_b, nullptr,
                                       nlwh, nlwl, nl_g_b, nl_p_b, nl_cp_w,
                                       vt, ct, nlWh, nlWl, nl_W_b, restored,
                                       Z, T, stats + SLOT);
    finalize_kernel<<<1, 256, 0, stream>>>(stats + SLOT, fin + 256);

    int sl = 1;
    for (int i = 0; i < NLAYERS; i++) {
        int l0 = 2 * i, l1 = 2 * i + 1, li = i + 1;
        // gconv1 + fused nl_b: z -> Z; t1 -> T, slot sl+1
        gconv_mfma_kernel<<<2048, 256, 0, stream>>>(
            Z, T, fin + (size_t)sl * 256,
            nl_bn_g + i * 128, nl_bn_b + i * 128, restored, Z,
            Wbh + (size_t)l0 * 32768, Wbl + (size_t)l0 * 32768, b_res + l0 * 128,
            off_all + (1 + l0) * 256, diag_all + (1 + l0) * 16, T,
            stats + (size_t)(sl + 1) * SLOT);
        finalize_kernel<<<1, 256, 0, stream>>>(stats + (size_t)(sl + 1) * SLOT,
                                               fin + (size_t)(sl + 1) * 256);
        // gconv2: t2 -> T, slot sl+2
        gconv_mfma_kernel<<<2048, 256, 0, stream>>>(
            T, nullptr, fin + (size_t)(sl + 1) * 256,
            bng_res + l0 * 128, bnb_res + l0 * 128, nullptr, nullptr,
            Wbh + (size_t)l1 * 32768, Wbl + (size_t)l1 * 32768, b_res + l1 * 128,
            off_all + (1 + l1) * 256, diag_all + (1 + l1) * 16, T,
            stats + (size_t)(sl + 2) * SLOT);
        finalize_kernel<<<1, 256, 0, stream>>>(stats + (size_t)(sl + 2) * SLOT,
                                               fin + (size_t)(sl + 2) * 256);
        // nl_a: h -> Z; wy -> T, slot sl+3
        nl_a_kernel<<<B, 512, 0, stream>>>(
            T, fin + (size_t)(sl + 2) * 256,
            bng_res + l1 * 128, bnb_res + l1 * 128, Z,
            nlwh + li * 24576, nlwl + li * 24576,
            nl_g_b + li * 64, nl_p_b + li * 64, nl_cp_w + li * 128,
            vt + li * 128, ct + li, nlWh + li * 8192, nlWl + li * 8192,
            nl_W_b + li * 128, restored, Z, T,
            stats + (size_t)(sl + 3) * SLOT);
        finalize_kernel<<<1, 256, 0, stream>>>(stats + (size_t)(sl + 3) * SLOT,
                                               fin + (size_t)(sl + 3) * 256);
        sl += 3;
    }
    gconv_out_kernel<<<B, 256, 0, stream>>>(Z, T, fin + (size_t)sl * 256,
                                            nl_bn_g + NLAYERS * 128, nl_bn_b + NLAYERS * 128,
                                            restored, gc_out_W, gc_out_b,
                                            off_all + 9 * 256, diag_all + 9 * 16,
                                            (float*)d_out);
}